// Round 1
// baseline (132.594 us; speedup 1.0000x reference)
//
#include <hip/hip_runtime.h>
#include <hip/hip_bf16.h>
#include <stdint.h>

#define NQ 10
#define DIMQ 1024
#define NLAYERS 4
#define BATCH 4096
#define NOUT 16

#define GM 4096
#define GN 2048
#define GK 1024

using f32x4 = __attribute__((ext_vector_type(4))) float;
using s16x8 = __attribute__((ext_vector_type(8))) short;

__device__ __forceinline__ float bf2f(unsigned short u) {
  union { unsigned int i; float f; } v; v.i = ((unsigned int)u) << 16; return v.f;
}
__device__ __forceinline__ unsigned short f2bf(float f) {
  union { float f; unsigned int i; } v; v.f = f;
  unsigned int x = v.i;
  return (unsigned short)((x + 0x7fffu + ((x >> 16) & 1u)) >> 16);  // RNE, finite inputs
}

// ---------------------------------------------------------------- build U ---
// Block k simulates the 80-gate circuit on basis state e_k; state (1024
// complex) lives in LDS. Writes column k of Ub (interleaved re/im rows,
// row-major [j][k] bf16) — scattered 2B writes, ~4MB total, absorbed by L2.
__global__ __launch_bounds__(256) void build_u(const float* __restrict__ wts,
                                               unsigned short* __restrict__ Ub) {
  __shared__ float2 st[DIMQ];
  __shared__ float gates[NLAYERS * NQ][8];
  int tid = threadIdx.x;
  int col = blockIdx.x;
  if (tid < NLAYERS * NQ) {
    float phi = wts[tid * 3 + 0], th = wts[tid * 3 + 1], om = wts[tid * 3 + 2];
    float ct = cosf(0.5f * th), s = sinf(0.5f * th);
    float ap = 0.5f * (phi + om), am = 0.5f * (phi - om);
    float cp = cosf(ap), spp = sinf(ap), cm = cosf(am), sm = sinf(am);
    float* G = gates[tid];
    G[0] = ct * cp;  G[1] = -ct * spp;   // a  = e^{-i(phi+om)/2} c
    G[2] = -s * cm;  G[3] = -s * sm;     // b  = -e^{+i(phi-om)/2} s
    G[4] = s * cm;   G[5] = -s * sm;     // c  = e^{-i(phi-om)/2} s
    G[6] = ct * cp;  G[7] = ct * spp;    // d  = e^{+i(phi+om)/2} c
  }
  for (int i = tid; i < DIMQ; i += 256)
    st[i] = make_float2(i == col ? 1.f : 0.f, 0.f);

  for (int l = 0; l < NLAYERS; ++l) {
    for (int q = 0; q < NQ; ++q) {           // qubit q <-> bit (9-q)
      __syncthreads();
      const float* G = gates[l * NQ + q];
      int m = 1 << (9 - q);
      #pragma unroll
      for (int t = tid; t < 512; t += 256) {
        int i0 = ((t & ~(m - 1)) << 1) | (t & (m - 1));
        int i1 = i0 | m;
        float2 s0 = st[i0], s1 = st[i1];
        float2 n0, n1;
        n0.x = G[0]*s0.x - G[1]*s0.y + G[2]*s1.x - G[3]*s1.y;
        n0.y = G[0]*s0.y + G[1]*s0.x + G[2]*s1.y + G[3]*s1.x;
        n1.x = G[4]*s0.x - G[5]*s0.y + G[6]*s1.x - G[7]*s1.y;
        n1.y = G[4]*s0.y + G[5]*s0.x + G[6]*s1.y + G[7]*s1.x;
        st[i0] = n0; st[i1] = n1;
      }
    }
    int r = (l % (NQ - 1)) + 1;
    for (int q = 0; q < NQ; ++q) {           // CNOT q -> (q+r)%10, in order
      int pc = 9 - q, pt = 9 - ((q + r) % NQ);
      int lo = pc < pt ? pc : pt, hi = pc ^ pt ^ lo;
      int lom = (1 << lo) - 1, him = (1 << hi) - 1;
      __syncthreads();
      int t = tid;                            // exactly 256 pairs
      int y = (t & lom) | ((t & ~lom) << 1);  // insert 0 at bit lo
      y = (y & him) | ((y & ~him) << 1);      // insert 0 at bit hi
      int i = y | (1 << pc);                  // control=1, target=0
      int j = i | (1 << pt);
      float2 a = st[i], b = st[j];
      st[i] = b; st[j] = a;                   // pairs disjoint: no intra-sync
    }
  }
  __syncthreads();
  for (int i = tid; i < DIMQ; i += 256) {
    Ub[(size_t)(2 * i)     * DIMQ + col] = f2bf(st[i].x);
    Ub[(size_t)(2 * i + 1) * DIMQ + col] = f2bf(st[i].y);
  }
}

// ------------------------------------------------------------- normalize ---
__global__ __launch_bounds__(256) void normalize_rows(const float* __restrict__ X,
                                                      unsigned short* __restrict__ Xn) {
  int lane = threadIdx.x & 63;
  int row = blockIdx.x * 4 + (threadIdx.x >> 6);
  const float* xr = X + (size_t)row * DIMQ;
  float4 v[4];
  float ss = 0.f;
  #pragma unroll
  for (int ii = 0; ii < 4; ++ii) {
    v[ii] = *(const float4*)(xr + ii * 256 + lane * 4);
    ss += v[ii].x*v[ii].x + v[ii].y*v[ii].y + v[ii].z*v[ii].z + v[ii].w*v[ii].w;
  }
  #pragma unroll
  for (int off = 32; off > 0; off >>= 1) ss += __shfl_xor(ss, off, 64);
  float rn = rsqrtf(ss);
  #pragma unroll
  for (int ii = 0; ii < 4; ++ii) {
    ushort4 o;
    o.x = f2bf(v[ii].x * rn); o.y = f2bf(v[ii].y * rn);
    o.z = f2bf(v[ii].z * rn); o.w = f2bf(v[ii].w * rn);
    *(ushort4*)(Xn + (size_t)row * DIMQ + ii * 256 + lane * 4) = o;
  }
}

// ------------------------------------------------------------------ GEMM ---
__device__ __forceinline__ void gload_lds16(const void* g, void* lds) {
  __builtin_amdgcn_global_load_lds(
      (const __attribute__((address_space(1))) unsigned int*)g,
      (__attribute__((address_space(3))) unsigned int*)lds, 16, 0, 0);
}

// C[b,j] = sum_k A[b,k]*B[j,k]; A=Xn (4096x1024 bf16), B=Ub (2048x1024 bf16),
// C=Y bf16. 128x128 tile, BK=64, 4 waves of 64x64, 16x16x32 MFMA.
// XOR chunk swizzle: LDS chunk (row,ch) holds global chunk ch^(row&7) so
// fragment ds_read_b128s spread over all 32 banks (2 lanes/bank = free).
__global__ __launch_bounds__(256) void gemm_bt(const unsigned short* __restrict__ A,
                                               const unsigned short* __restrict__ B,
                                               unsigned short* __restrict__ C) {
  __shared__ char lds[32768];
  char* As = lds;
  char* Bs = lds + 16384;
  int tid = threadIdx.x;
  int lane = tid & 63;
  int w = tid >> 6;
  int mtile = blockIdx.x & 31;
  int ntile = blockIdx.x >> 5;
  int wm = (w & 1) * 64;
  int wn = (w >> 1) * 64;
  const unsigned short* Ag = A + (size_t)mtile * 128 * GK;
  const unsigned short* Bg = B + (size_t)ntile * 128 * GK;
  f32x4 acc[4][4];
  #pragma unroll
  for (int i = 0; i < 4; ++i)
    #pragma unroll
    for (int j = 0; j < 4; ++j) acc[i][j] = (f32x4){0.f, 0.f, 0.f, 0.f};

  for (int kt = 0; kt < GK; kt += 64) {
    __syncthreads();
    #pragma unroll
    for (int s = 0; s < 4; ++s) {
      int chunk = (w << 8) | (s << 6) | lane;   // 0..1023 over the 4 waves
      int row = chunk >> 3, ch = chunk & 7;
      int sch = ch ^ (row & 7);                 // which global chunk lands here
      gload_lds16(Ag + (size_t)row * GK + kt + sch * 8, As + (((w << 2) + s) << 10));
      gload_lds16(Bg + (size_t)row * GK + kt + sch * 8, Bs + (((w << 2) + s) << 10));
    }
    __builtin_amdgcn_s_waitcnt(0);
    __syncthreads();
    #pragma unroll
    for (int ks = 0; ks < 2; ++ks) {
      s16x8 af[4], bfr[4];
      #pragma unroll
      for (int mt = 0; mt < 4; ++mt) {
        int rowa = wm + mt * 16 + (lane & 15);
        int kc = (ks << 2) + (lane >> 4);
        af[mt] = *(const s16x8*)(As + (((rowa << 3) + (kc ^ (rowa & 7))) << 4));
        int rowb = wn + mt * 16 + (lane & 15);
        bfr[mt] = *(const s16x8*)(Bs + (((rowb << 3) + (kc ^ (rowb & 7))) << 4));
      }
      #pragma unroll
      for (int mt = 0; mt < 4; ++mt)
        #pragma unroll
        for (int nt = 0; nt < 4; ++nt)
          acc[mt][nt] = __builtin_amdgcn_mfma_f32_16x16x32_bf16(af[mt], bfr[nt],
                                                                acc[mt][nt], 0, 0, 0);
    }
  }
  int quad = lane >> 4, cn = lane & 15;
  #pragma unroll
  for (int mt = 0; mt < 4; ++mt)
    #pragma unroll
    for (int nt = 0; nt < 4; ++nt)
      #pragma unroll
      for (int r = 0; r < 4; ++r) {
        int gm = mtile * 128 + wm + mt * 16 + quad * 4 + r;
        int gn = ntile * 128 + wn + nt * 16 + cn;
        C[(size_t)gm * GN + gn] = f2bf(acc[mt][nt][r]);
      }
}

// ---------------------------------------------------------------- reduce ---
// out[b,o] = bias[o] + sum_q z_q W[o,q];  z_q = sum_i sign(i,q)*(yr^2+yi^2)
__global__ __launch_bounds__(256) void reduce_out(const unsigned short* __restrict__ Y,
                                                  const float* __restrict__ W,
                                                  const float* __restrict__ bias,
                                                  float* __restrict__ out) {
  int lane = threadIdx.x & 63;
  int row = blockIdx.x * 4 + (threadIdx.x >> 6);
  const unsigned short* yr = Y + (size_t)row * 2048;
  float z[10];
  #pragma unroll
  for (int q = 0; q < 10; ++q) z[q] = 0.f;
  #pragma unroll
  for (int ii = 0; ii < 16; ++ii) {
    int i = ii * 64 + lane;
    ushort2 u = *(const ushort2*)(yr + 2 * i);
    float re = bf2f(u.x), im = bf2f(u.y);
    float p = re * re + im * im;
    #pragma unroll
    for (int q = 0; q < 10; ++q)
      z[q] += ((i >> (9 - q)) & 1) ? -p : p;
  }
  #pragma unroll
  for (int q = 0; q < 10; ++q)
    #pragma unroll
    for (int off = 32; off > 0; off >>= 1) z[q] += __shfl_xor(z[q], off, 64);
  if (lane < 16) {
    float acc = bias[lane];
    #pragma unroll
    for (int q = 0; q < 10; ++q) acc += z[q] * W[lane * 10 + q];
    out[(size_t)row * 16 + lane] = acc;
  }
}

extern "C" void kernel_launch(void* const* d_in, const int* in_sizes, int n_in,
                              void* d_out, int out_size, void* d_ws, size_t ws_size,
                              hipStream_t stream) {
  const float* X    = (const float*)d_in[0];
  const float* wts  = (const float*)d_in[1];
  const float* W    = (const float*)d_in[2];
  const float* bias = (const float*)d_in[3];
  float* out = (float*)d_out;
  char* ws = (char*)d_ws;
  unsigned short* Xn = (unsigned short*)ws;                       // 8 MB
  unsigned short* Ub = (unsigned short*)(ws + 8u  * 1024 * 1024); // 4 MB
  unsigned short* Y  = (unsigned short*)(ws + 12u * 1024 * 1024); // 16 MB

  hipLaunchKernelGGL(normalize_rows, dim3(BATCH / 4), dim3(256), 0, stream, X, Xn);
  hipLaunchKernelGGL(build_u,        dim3(DIMQ),      dim3(256), 0, stream, wts, Ub);
  hipLaunchKernelGGL(gemm_bt,        dim3((GM/128)*(GN/128)), dim3(256), 0, stream, Xn, Ub, Y);
  hipLaunchKernelGGL(reduce_out,     dim3(BATCH / 4), dim3(256), 0, stream, Y, W, bias, out);
}

// Round 2
// 128.379 us; speedup vs baseline: 1.0328x; 1.0328x over previous
//
#include <hip/hip_runtime.h>
#include <hip/hip_bf16.h>
#include <stdint.h>

#define NQ 10
#define DIMQ 1024
#define NLAYERS 4
#define BATCH 4096
#define NOUT 16

#define GM 4096
#define GN 2048
#define GK 1024

using f32x4 = __attribute__((ext_vector_type(4))) float;
using s16x8 = __attribute__((ext_vector_type(8))) short;

__device__ __forceinline__ float bf2f(unsigned short u) {
  union { unsigned int i; float f; } v; v.i = ((unsigned int)u) << 16; return v.f;
}
__device__ __forceinline__ unsigned short f2bf(float f) {
  union { float f; unsigned int i; } v; v.f = f;
  unsigned int x = v.i;
  return (unsigned short)((x + 0x7fffu + ((x >> 16) & 1u)) >> 16);  // RNE, finite inputs
}

// GF(2)-linear gather map of one full CNOT layer (shift r), compile-time
// foldable. s_after[j] = s_before[cnot_map(j, r)]: CNOTs applied q=0..9 in
// order; gather composition applies q=9 innermost.
__device__ __forceinline__ int cnot_map(int j, int r) {
  #pragma unroll
  for (int q = 9; q >= 0; --q) {
    int pc = 9 - q, pt = 9 - ((q + r) % NQ);
    j ^= ((j >> pc) & 1) << pt;
  }
  return j;
}

// ---------------------------------------------------------------- build U ---
// Block b simulates basis columns {2b, 2b+1}. State SoA float in LDS,
// col-interleaved (stR[i*2+col]) -> b32 LDS ops, 2 lanes/bank (free) for
// gates on high bits. 40 rotation sync-steps + 4 fused CNOT-layer gathers.
__global__ __launch_bounds__(256) void build_u(const float* __restrict__ wts,
                                               unsigned short* __restrict__ Ub) {
  __shared__ float stR[2 * DIMQ];
  __shared__ float stI[2 * DIMQ];
  __shared__ float gates[NLAYERS * NQ][8];
  int tid = threadIdx.x;
  int col = tid & 1;
  int tslot = tid >> 1;
  int colg = blockIdx.x * 2 + col;

  if (tid < NLAYERS * NQ) {
    float phi = wts[tid * 3 + 0], th = wts[tid * 3 + 1], om = wts[tid * 3 + 2];
    float ct = cosf(0.5f * th), s = sinf(0.5f * th);
    float ap = 0.5f * (phi + om), am = 0.5f * (phi - om);
    float cp = cosf(ap), spp = sinf(ap), cm = cosf(am), sm = sinf(am);
    float* G = gates[tid];
    G[0] = ct * cp;  G[1] = -ct * spp;   // a = e^{-i(phi+om)/2} c
    G[2] = -s * cm;  G[3] = -s * sm;     // b = -e^{+i(phi-om)/2} s
    G[4] = s * cm;   G[5] = -s * sm;     // c = e^{-i(phi-om)/2} s
    G[6] = ct * cp;  G[7] = ct * spp;    // d = e^{+i(phi+om)/2} c
  }
  #pragma unroll
  for (int e = 0; e < 8; ++e) {
    int idx = e * 256 + tid;
    int i = idx >> 1, c = idx & 1;
    stR[idx] = (i == blockIdx.x * 2 + c) ? 1.f : 0.f;
    stI[idx] = 0.f;
  }

  #pragma unroll
  for (int l = 0; l < NLAYERS; ++l) {
    #pragma unroll
    for (int q = 0; q < NQ; ++q) {           // qubit q <-> bit (9-q)
      __syncthreads();
      const float* G = gates[l * NQ + q];
      float G0 = G[0], G1 = G[1], G2 = G[2], G3 = G[3];
      float G4 = G[4], G5 = G[5], G6 = G[6], G7 = G[7];
      const int m = 1 << (9 - q);
      #pragma unroll
      for (int s = 0; s < 4; ++s) {
        int t = s * 128 + tslot;
        int i0 = ((t & ~(m - 1)) << 1) | (t & (m - 1));
        int i1 = i0 | m;
        int x0 = i0 * 2 + col, x1 = i1 * 2 + col;
        float r0 = stR[x0], u0 = stI[x0], r1 = stR[x1], u1 = stI[x1];
        float nr0 = G0 * r0 - G1 * u0 + G2 * r1 - G3 * u1;
        float ni0 = G0 * u0 + G1 * r0 + G2 * u1 + G3 * r1;
        float nr1 = G4 * r0 - G5 * u0 + G6 * r1 - G7 * u1;
        float ni1 = G4 * u0 + G5 * r0 + G6 * u1 + G7 * r1;
        stR[x0] = nr0; stI[x0] = ni0; stR[x1] = nr1; stI[x1] = ni1;
      }
    }
    // fused CNOT layer: one gather pass. G linear over GF(2):
    // G(s*128 + tslot) = G(s*128) ^ G(tslot); G(s*128) constant-folds.
    const int r = l % (NQ - 1) + 1;
    float gr[8], gi[8];
    int gb = cnot_map(tslot, r);
    __syncthreads();
    #pragma unroll
    for (int s = 0; s < 8; ++s) {
      int g = gb ^ cnot_map(s * 128, r);
      gr[s] = stR[g * 2 + col];
      gi[s] = stI[g * 2 + col];
    }
    __syncthreads();
    #pragma unroll
    for (int s = 0; s < 8; ++s) {
      int j = s * 128 + tslot;
      stR[j * 2 + col] = gr[s];
      stI[j * 2 + col] = gi[s];
    }
  }
  __syncthreads();
  #pragma unroll
  for (int s = 0; s < 8; ++s) {
    int i = s * 128 + tslot;
    Ub[(size_t)(2 * i)     * DIMQ + colg] = f2bf(stR[i * 2 + col]);
    Ub[(size_t)(2 * i + 1) * DIMQ + colg] = f2bf(stI[i * 2 + col]);
  }
}

// ------------------------------------------------------------- normalize ---
__global__ __launch_bounds__(256) void normalize_rows(const float* __restrict__ X,
                                                      unsigned short* __restrict__ Xn) {
  int lane = threadIdx.x & 63;
  int row = blockIdx.x * 4 + (threadIdx.x >> 6);
  const float* xr = X + (size_t)row * DIMQ;
  float4 v[4];
  float ss = 0.f;
  #pragma unroll
  for (int ii = 0; ii < 4; ++ii) {
    v[ii] = *(const float4*)(xr + ii * 256 + lane * 4);
    ss += v[ii].x*v[ii].x + v[ii].y*v[ii].y + v[ii].z*v[ii].z + v[ii].w*v[ii].w;
  }
  #pragma unroll
  for (int off = 32; off > 0; off >>= 1) ss += __shfl_xor(ss, off, 64);
  float rn = rsqrtf(ss);
  #pragma unroll
  for (int ii = 0; ii < 4; ++ii) {
    ushort4 o;
    o.x = f2bf(v[ii].x * rn); o.y = f2bf(v[ii].y * rn);
    o.z = f2bf(v[ii].z * rn); o.w = f2bf(v[ii].w * rn);
    *(ushort4*)(Xn + (size_t)row * DIMQ + ii * 256 + lane * 4) = o;
  }
}

// ------------------------------------------------------------------ GEMM ---
__device__ __forceinline__ void gload_lds16(const void* g, void* lds) {
  __builtin_amdgcn_global_load_lds(
      (const __attribute__((address_space(1))) unsigned int*)g,
      (__attribute__((address_space(3))) unsigned int*)lds, 16, 0, 0);
}

// C[b,j] = sum_k A[b,k]*B[j,k]; A=Xn (4096x1024 bf16), B=Ub (2048x1024 bf16),
// C=Y bf16. 128x128 tile, BK=64, 4 waves of 64x64, 16x16x32 MFMA.
// XOR chunk swizzle: LDS chunk (row,ch) holds global chunk ch^(row&7) so
// fragment ds_read_b128s spread over all 32 banks (2 lanes/bank = free).
__global__ __launch_bounds__(256) void gemm_bt(const unsigned short* __restrict__ A,
                                               const unsigned short* __restrict__ B,
                                               unsigned short* __restrict__ C) {
  __shared__ char lds[32768];
  char* As = lds;
  char* Bs = lds + 16384;
  int tid = threadIdx.x;
  int lane = tid & 63;
  int w = tid >> 6;
  int mtile = blockIdx.x & 31;
  int ntile = blockIdx.x >> 5;
  int wm = (w & 1) * 64;
  int wn = (w >> 1) * 64;
  const unsigned short* Ag = A + (size_t)mtile * 128 * GK;
  const unsigned short* Bg = B + (size_t)ntile * 128 * GK;
  f32x4 acc[4][4];
  #pragma unroll
  for (int i = 0; i < 4; ++i)
    #pragma unroll
    for (int j = 0; j < 4; ++j) acc[i][j] = (f32x4){0.f, 0.f, 0.f, 0.f};

  for (int kt = 0; kt < GK; kt += 64) {
    __syncthreads();
    #pragma unroll
    for (int s = 0; s < 4; ++s) {
      int chunk = (w << 8) | (s << 6) | lane;   // 0..1023 over the 4 waves
      int row = chunk >> 3, ch = chunk & 7;
      int sch = ch ^ (row & 7);                 // which global chunk lands here
      gload_lds16(Ag + (size_t)row * GK + kt + sch * 8, As + (((w << 2) + s) << 10));
      gload_lds16(Bg + (size_t)row * GK + kt + sch * 8, Bs + (((w << 2) + s) << 10));
    }
    __builtin_amdgcn_s_waitcnt(0);
    __syncthreads();
    #pragma unroll
    for (int ks = 0; ks < 2; ++ks) {
      s16x8 af[4], bfr[4];
      #pragma unroll
      for (int mt = 0; mt < 4; ++mt) {
        int rowa = wm + mt * 16 + (lane & 15);
        int kc = (ks << 2) + (lane >> 4);
        af[mt] = *(const s16x8*)(As + (((rowa << 3) + (kc ^ (rowa & 7))) << 4));
        int rowb = wn + mt * 16 + (lane & 15);
        bfr[mt] = *(const s16x8*)(Bs + (((rowb << 3) + (kc ^ (rowb & 7))) << 4));
      }
      #pragma unroll
      for (int mt = 0; mt < 4; ++mt)
        #pragma unroll
        for (int nt = 0; nt < 4; ++nt)
          acc[mt][nt] = __builtin_amdgcn_mfma_f32_16x16x32_bf16(af[mt], bfr[nt],
                                                                acc[mt][nt], 0, 0, 0);
    }
  }
  int quad = lane >> 4, cn = lane & 15;
  #pragma unroll
  for (int mt = 0; mt < 4; ++mt)
    #pragma unroll
    for (int nt = 0; nt < 4; ++nt)
      #pragma unroll
      for (int r = 0; r < 4; ++r) {
        int gm = mtile * 128 + wm + mt * 16 + quad * 4 + r;
        int gn = ntile * 128 + wn + nt * 16 + cn;
        C[(size_t)gm * GN + gn] = f2bf(acc[mt][nt][r]);
      }
}

// ---------------------------------------------------------------- reduce ---
// out[b,o] = bias[o] + sum_q z_q W[o,q];  z_q = sum_i sign(i,q)*(yr^2+yi^2)
__global__ __launch_bounds__(256) void reduce_out(const unsigned short* __restrict__ Y,
                                                  const float* __restrict__ W,
                                                  const float* __restrict__ bias,
                                                  float* __restrict__ out) {
  int lane = threadIdx.x & 63;
  int row = blockIdx.x * 4 + (threadIdx.x >> 6);
  const unsigned short* yr = Y + (size_t)row * 2048;
  float z[10];
  #pragma unroll
  for (int q = 0; q < 10; ++q) z[q] = 0.f;
  #pragma unroll
  for (int ii = 0; ii < 16; ++ii) {
    int i = ii * 64 + lane;
    ushort2 u = *(const ushort2*)(yr + 2 * i);
    float re = bf2f(u.x), im = bf2f(u.y);
    float p = re * re + im * im;
    #pragma unroll
    for (int q = 0; q < 10; ++q)
      z[q] += ((i >> (9 - q)) & 1) ? -p : p;
  }
  #pragma unroll
  for (int q = 0; q < 10; ++q)
    #pragma unroll
    for (int off = 32; off > 0; off >>= 1) z[q] += __shfl_xor(z[q], off, 64);
  if (lane < 16) {
    float acc = bias[lane];
    #pragma unroll
    for (int q = 0; q < 10; ++q) acc += z[q] * W[lane * 10 + q];
    out[(size_t)row * 16 + lane] = acc;
  }
}

extern "C" void kernel_launch(void* const* d_in, const int* in_sizes, int n_in,
                              void* d_out, int out_size, void* d_ws, size_t ws_size,
                              hipStream_t stream) {
  const float* X    = (const float*)d_in[0];
  const float* wts  = (const float*)d_in[1];
  const float* W    = (const float*)d_in[2];
  const float* bias = (const float*)d_in[3];
  float* out = (float*)d_out;
  char* ws = (char*)d_ws;
  unsigned short* Xn = (unsigned short*)ws;                       // 8 MB
  unsigned short* Ub = (unsigned short*)(ws + 8u  * 1024 * 1024); // 4 MB
  unsigned short* Y  = (unsigned short*)(ws + 12u * 1024 * 1024); // 16 MB

  hipLaunchKernelGGL(normalize_rows, dim3(BATCH / 4), dim3(256), 0, stream, X, Xn);
  hipLaunchKernelGGL(build_u,        dim3(DIMQ / 2),  dim3(256), 0, stream, wts, Ub);
  hipLaunchKernelGGL(gemm_bt,        dim3((GM/128)*(GN/128)), dim3(256), 0, stream, Xn, Ub, Y);
  hipLaunchKernelGGL(reduce_out,     dim3(BATCH / 4), dim3(256), 0, stream, Y, W, bias, out);
}